// Round 10
// baseline (780.331 us; speedup 1.0000x reference)
//
#include <hip/hip_runtime.h>
#include <cstdint>

#define NCLS 60
#define KC 512
#define DD 256
#define BB 32
#define NP 4096
#define LDP 260
#define EPS 1e-2f     // fp16-vs-np dist divergence window (bound ~1e-3)
#define FIX_CAP 32768

typedef _Float16 f16;
typedef _Float16 f16x8 __attribute__((ext_vector_type(8)));
typedef float f32x4 __attribute__((ext_vector_type(4)));

// Rounded fp32 multiply that cannot fuse into a following add (np-exact path).
__device__ __forceinline__ float mul_rn_nofuse(float a, float b) {
  float p = a * b;
  asm("" : "+v"(p));
  return p;
}

// numpy pairwise_sum of x*x over 256 contiguous floats.
__device__ __forceinline__ float np_pairwise256_sq(const float* row) {
  float h0 = 0.f, h1 = 0.f;
#pragma unroll
  for (int half = 0; half < 2; ++half) {
    const float* a = row + half * 128;
    float r[8];
#pragma unroll
    for (int j = 0; j < 8; ++j) r[j] = mul_rn_nofuse(a[j], a[j]);
    for (int blk = 1; blk < 16; ++blk) {
#pragma unroll
      for (int j = 0; j < 8; ++j) {
        float p = mul_rn_nofuse(a[blk * 8 + j], a[blk * 8 + j]);
        r[j] = r[j] + p;
      }
    }
    float res = ((r[0] + r[1]) + (r[2] + r[3])) + ((r[4] + r[5]) + (r[6] + r[7]));
    if (half == 0) h0 = res; else h1 = res;
  }
  return h0 + h1;
}

// np-einsum SSE-order dot over 256 floats (gold-validated rounds 3-9).
__device__ __forceinline__ float np_dot256(const float* __restrict__ zr,
                                           const float* __restrict__ cr) {
  float A0 = 0.f, A1 = 0.f, A2 = 0.f, A3 = 0.f;
#pragma unroll 1
  for (int c16 = 0; c16 < 16; ++c16) {
    const float* zz = zr + c16 * 16;
    const float* cc = cr + c16 * 16;
#pragma unroll
    for (int s = 3; s >= 0; --s) {
      A0 = mul_rn_nofuse(zz[s * 4 + 0], cc[s * 4 + 0]) + A0;
      A1 = mul_rn_nofuse(zz[s * 4 + 1], cc[s * 4 + 1]) + A1;
      A2 = mul_rn_nofuse(zz[s * 4 + 2], cc[s * 4 + 2]) + A2;
      A3 = mul_rn_nofuse(zz[s * 4 + 3], cc[s * 4 + 3]) + A3;
    }
  }
  return (A0 + A1) + (A2 + A3);
}

// ---- prep: np-exact z_sq + fp16 transpose zT_h[b][n][d] (into d_out) ----
__global__ __launch_bounds__(64) void zprep_kernel(const float* __restrict__ z,
                                                   float* __restrict__ zsq,
                                                   f16* __restrict__ zT_h) {
  __shared__ float zs[64][LDP];
  int t = threadIdx.x;
  int b = blockIdx.x >> 6;
  int n0 = (blockIdx.x & 63) * 64;
  const float* zb = z + (size_t)b * DD * NP;
  for (int d = 0; d < DD; ++d) zs[t][d] = zb[(size_t)d * NP + n0 + t];
  __syncthreads();
  zsq[b * NP + n0 + t] = np_pairwise256_sq(&zs[t][0]);
  f16* ob = zT_h + ((size_t)b * NP + n0) * DD;
  for (int it = 0; it < 64; ++it) {   // coalesced: 64 lanes x 8B = one row
    union { f16 h[4]; uint2 u; } pk;
#pragma unroll
    for (int j = 0; j < 4; ++j) pk.h[j] = (f16)zs[it][t * 4 + j];
    *(uint2*)&ob[(size_t)it * DD + t * 4] = pk.u;
  }
}

// ---- prep: np-exact cb_sq + fp16 codebook copy (into d_out) ----
__global__ __launch_bounds__(64) void cbprep_kernel(const float* __restrict__ emb,
                                                    float* __restrict__ cbsq,
                                                    f16* __restrict__ cb_h) {
  __shared__ float cs[64][LDP];
  int t = threadIdx.x;
  int r0 = blockIdx.x * 64;
  const float4* e4 = (const float4*)emb;
  for (int rr = 0; rr < 64; ++rr) {
    float4 v = e4[(size_t)(r0 + rr) * 64 + t];
    *(float4*)&cs[rr][t * 4] = v;
  }
  __syncthreads();
  cbsq[r0 + t] = np_pairwise256_sq(&cs[t][0]);
  for (int rr = 0; rr < 64; ++rr) {
    union { f16 h[4]; uint2 u; } pk;
#pragma unroll
    for (int j = 0; j < 4; ++j) pk.h[j] = (f16)cs[rr][t * 4 + j];
    *(uint2*)&cb_h[(size_t)(r0 + rr) * DD + t * 4] = pk.u;
  }
}

// ---- phase 1: fp16 MFMA distances + top-2 argmin; near-ties flagged ----
// Block 256 thr = 4 waves (2m x 2n), block tile 128n x 128k, wave 64x64.
// A-frag: lane holds zs[m=l&15][k-chunk (l>>4)*8]; B: cs[n=l&15][same] —
// C/D per m89: col=lane&15, row=(lane>>4)*4+reg.
__global__ __launch_bounds__(256) void vq_mfma_kernel(
    const f16* __restrict__ zT_h, const int* __restrict__ c,
    const f16* __restrict__ cb_h, const float* __restrict__ zsq,
    const float* __restrict__ cbsq, int* __restrict__ idx_out,
    unsigned int* __restrict__ counter, unsigned int* __restrict__ fixlist) {
  __shared__ __align__(16) f16 zs[128][72];  // 18.4 KB, stride 144B (balanced quads)
  __shared__ __align__(16) f16 cs[128][72];
  const int t = threadIdx.x;
  const int b = blockIdx.y;
  const int n0 = blockIdx.x * 128;
  const int wave = t >> 6;
  const int wm = wave >> 1, wn = wave & 1;
  const int l = t & 63, lr = l & 15, lg = l >> 4;
  const int cls = c[b];
  const f16* __restrict__ zTb = zT_h + ((size_t)b * NP + n0) * DD;
  const f16* __restrict__ cbb = cb_h + (size_t)cls * KC * DD;
  const float* __restrict__ cbsqb = cbsq + cls * KC;
  const int srow = t >> 1, sh = t & 1;  // staging: 2 threads/row, 64B each

  float zsqv[16];
#pragma unroll
  for (int mi = 0; mi < 4; ++mi)
#pragma unroll
    for (int rg = 0; rg < 4; ++rg)
      zsqv[mi * 4 + rg] = zsq[b * NP + n0 + wm * 64 + mi * 16 + lg * 4 + rg];

  float m1[16], m2[16];
  int i1[16];
#pragma unroll
  for (int r = 0; r < 16; ++r) { m1[r] = 3.4e38f; m2[r] = 3.4e38f; i1[r] = 0; }

#pragma unroll 1
  for (int kt = 0; kt < 4; ++kt) {
    const int k0 = kt * 128;
    f32x4 acc[4][4];
#pragma unroll
    for (int mi = 0; mi < 4; ++mi)
#pragma unroll
      for (int nj = 0; nj < 4; ++nj) acc[mi][nj] = (f32x4){0.f, 0.f, 0.f, 0.f};

#pragma unroll 1
    for (int dc = 0; dc < 4; ++dc) {
      const int d0g = dc * 64;
      __syncthreads();
      {  // stage z tile [128][64] f16, b128 both sides
        const f16* gz = zTb + (size_t)srow * DD + d0g + sh * 32;
        f16* lz = &zs[srow][sh * 32];
#pragma unroll
        for (int i = 0; i < 4; ++i)
          *(f16x8*)(lz + i * 8) = *(const f16x8*)(gz + i * 8);
        const f16* gc = cbb + (size_t)(k0 + srow) * DD + d0g + sh * 32;
        f16* lc = &cs[srow][sh * 32];
#pragma unroll
        for (int i = 0; i < 4; ++i)
          *(f16x8*)(lc + i * 8) = *(const f16x8*)(gc + i * 8);
      }
      __syncthreads();
#pragma unroll
      for (int s = 0; s < 2; ++s) {
        const int d0 = s * 32 + lg * 8;
        f16x8 af[4], bf[4];
#pragma unroll
        for (int mi = 0; mi < 4; ++mi)
          af[mi] = *(const f16x8*)&zs[wm * 64 + mi * 16 + lr][d0];
#pragma unroll
        for (int nj = 0; nj < 4; ++nj)
          bf[nj] = *(const f16x8*)&cs[wn * 64 + nj * 16 + lr][d0];
#pragma unroll
        for (int mi = 0; mi < 4; ++mi)
#pragma unroll
          for (int nj = 0; nj < 4; ++nj)
            acc[mi][nj] = __builtin_amdgcn_mfma_f32_16x16x32_f16(
                af[mi], bf[nj], acc[mi][nj], 0, 0, 0);
      }
    }

    // epilogue: dist + per-row top-2 (k ascending per thread)
#pragma unroll
    for (int nj = 0; nj < 4; ++nj) {
      const int k = k0 + wn * 64 + nj * 16 + lr;
      const float cq = cbsqb[k];
#pragma unroll
      for (int mi = 0; mi < 4; ++mi)
#pragma unroll
        for (int rg = 0; rg < 4; ++rg) {
          const int ri = mi * 4 + rg;
          float dist = (zsqv[ri] - 2.0f * acc[mi][nj][rg]) + cq;
          if (dist < m1[ri]) {
            m2[ri] = m1[ri]; m1[ri] = dist; i1[ri] = k;
          } else if (dist < m2[ri]) {
            m2[ri] = dist;
          }
        }
    }
  }

  // top-2 butterfly across the 16 lanes (lr) sharing each row set
#pragma unroll
  for (int r = 0; r < 16; ++r) {
#pragma unroll
    for (int off = 8; off >= 1; off >>= 1) {
      float om1 = __shfl_xor(m1[r], off);
      float om2 = __shfl_xor(m2[r], off);
      int oi = __shfl_xor(i1[r], off);
      bool take = (om1 < m1[r]) || (om1 == m1[r] && oi < i1[r]);
      if (take) {
        m2[r] = fminf(m1[r], om2);
        m1[r] = om1;
        i1[r] = oi;
      } else {
        m2[r] = fminf(m2[r], om1);
      }
    }
  }

  // cross-wave (wn halves) merge via LDS overlay on zs
  __syncthreads();
  float* redm = (float*)&zs[0][0];        // [2][128][2] floats
  int* redi = (int*)(redm + 512);         // [2][128]
  if (lr == 0) {
#pragma unroll
    for (int r = 0; r < 16; ++r) {
      int row = wm * 64 + (r >> 2) * 16 + lg * 4 + (r & 3);
      redm[(wn * 128 + row) * 2 + 0] = m1[r];
      redm[(wn * 128 + row) * 2 + 1] = m2[r];
      redi[wn * 128 + row] = i1[r];
    }
  }
  __syncthreads();
  if (t < 128) {
    const int row = t;
    float a1 = redm[row * 2], a2 = redm[row * 2 + 1];
    int ai = redi[row];
    float b1 = redm[(128 + row) * 2], b2 = redm[(128 + row) * 2 + 1];
    int bi2 = redi[128 + row];
    float f1, f2;
    int idx;
    if (b1 < a1) { f1 = b1; idx = bi2; f2 = fminf(a1, b2); }
    else { f1 = a1; idx = ai; f2 = fminf(b1, a2); }
    const int n = n0 + row;
    idx_out[b * NP + n] = idx;
    if (f2 - f1 < EPS) {
      unsigned p = atomicAdd(counter, 1u);
      if (p < FIX_CAP) fixlist[p] = ((unsigned)b << 12) | (unsigned)n;
    }
  }
}

// ---- phase 2: np-exact re-resolution (all 512 k) of flagged positions ----
__global__ __launch_bounds__(256) void vq_fix_kernel(
    const float* __restrict__ z, const int* __restrict__ c,
    const float* __restrict__ emb, const float* __restrict__ zsq,
    const float* __restrict__ cbsq, int* __restrict__ idx_out,
    const unsigned int* __restrict__ counter,
    const unsigned int* __restrict__ fixlist) {
  unsigned cnt = *counter;
  if (cnt > FIX_CAP) cnt = FIX_CAP;
  if (blockIdx.x >= cnt) return;
  unsigned packed = fixlist[blockIdx.x];
  int b = (int)(packed >> 12);
  int n = (int)(packed & (NP - 1));
  int t = threadIdx.x;

  __shared__ __align__(16) float zrow[DD];
  zrow[t] = z[((size_t)b * DD + t) * NP + n];  // strided gather of one z row
  __syncthreads();

  const int cls = c[b];
  const float zsq_n = zsq[b * NP + n];
  const float* cbc = emb + (size_t)cls * KC * DD;

  float best = 3.4e38f;
  int bk = 0;
#pragma unroll
  for (int kk = 0; kk < 2; ++kk) {
    int k = t + kk * 256;
    float dot = np_dot256(zrow, cbc + (size_t)k * DD);
    float dist = (zsq_n - 2.0f * dot) + cbsq[cls * KC + k];
    if (dist < best) { best = dist; bk = k; }
  }

  __shared__ float rb[256];
  __shared__ int ri[256];
  rb[t] = best;
  ri[t] = bk;
  __syncthreads();
  for (int off = 128; off >= 1; off >>= 1) {
    if (t < off) {
      float ob = rb[t + off];
      int oi = ri[t + off];
      if (ob < rb[t] || (ob == rb[t] && oi < ri[t])) { rb[t] = ob; ri[t] = oi; }
    }
    __syncthreads();
  }
  if (t == 0) idx_out[b * NP + n] = ri[0];
}

// ---- gather selected rows -> [B,H,W,D] (bitwise copy; overwrites d_out) ----
__global__ __launch_bounds__(256) void vq_gather_kernel(
    const int* __restrict__ c, const float* __restrict__ emb,
    const int* __restrict__ idx, float* __restrict__ out) {
  int t = threadIdx.x;
  int r = blockIdx.x * 4 + (t >> 6);
  int lane = t & 63;
  int b = r >> 12;
  int k = idx[r];
  const float4* src = (const float4*)(emb + (size_t)(c[b] * KC + k) * DD);
  float4* dst = (float4*)(out + (size_t)r * DD);
  dst[lane] = src[lane];
}

extern "C" void kernel_launch(void* const* d_in, const int* in_sizes, int n_in,
                              void* d_out, int out_size, void* d_ws, size_t ws_size,
                              hipStream_t stream) {
  const float* z = (const float*)d_in[0];    // [32,256,64,64]
  const int* c = (const int*)d_in[1];        // [32]
  const float* emb = (const float*)d_in[2];  // [30720,256]
  float* out = (float*)d_out;                // [32,64,64,256] = 134.2 MB

  char* ws = (char*)d_ws;
  float* zsq = (float*)ws;                                 // 512 KB
  float* cbsq = (float*)(ws + 524288);                     // 120 KB
  int* idx = (int*)(ws + 655360);                          // 512 KB
  unsigned int* counter = (unsigned int*)(ws + 1179648);
  unsigned int* fixlist = counter + 1;                     // 128 KB

  // d_out doubles as fp16 scratch: zT_h (67.1 MB) + cb_h (15.7 MB);
  // gather fully overwrites d_out at the end.
  f16* zT_h = (f16*)d_out;
  f16* cb_h = (f16*)((char*)d_out + (size_t)BB * NP * DD * 2);

  hipMemsetAsync(counter, 0, sizeof(unsigned int), stream);
  zprep_kernel<<<BB * (NP / 64), 64, 0, stream>>>(z, zsq, zT_h);
  cbprep_kernel<<<(NCLS * KC) / 64, 64, 0, stream>>>(emb, cbsq, cb_h);
  dim3 gA(NP / 128, BB);
  vq_mfma_kernel<<<gA, 256, 0, stream>>>(zT_h, c, cb_h, zsq, cbsq, idx, counter, fixlist);
  vq_fix_kernel<<<FIX_CAP, 256, 0, stream>>>(z, c, emb, zsq, cbsq, idx, counter, fixlist);
  vq_gather_kernel<<<(BB * NP) / 4, 256, 0, stream>>>(c, emb, idx, out);
}

// Round 11
// 576.974 us; speedup vs baseline: 1.3525x; 1.3525x over previous
//
#include <hip/hip_runtime.h>
#include <cstdint>

#define NCLS 60
#define KC 512
#define DD 256
#define BB 32
#define NP 4096
#define LDP 260
#define EPS 1e-2f      // provable fp16-vs-np dist bound ~9e-3
#define PER_CLS 2048   // per-class fixlist capacity (worst realistic ~1500)

typedef _Float16 f16;
typedef _Float16 f16x8 __attribute__((ext_vector_type(8)));
typedef float f32x4 __attribute__((ext_vector_type(4)));

__device__ __forceinline__ float mul_rn_nofuse(float a, float b) {
  float p = a * b;
  asm("" : "+v"(p));
  return p;
}

// numpy pairwise_sum of x*x over 256 contiguous floats.
__device__ __forceinline__ float np_pairwise256_sq(const float* row) {
  float h0 = 0.f, h1 = 0.f;
#pragma unroll
  for (int half = 0; half < 2; ++half) {
    const float* a = row + half * 128;
    float r[8];
#pragma unroll
    for (int j = 0; j < 8; ++j) r[j] = mul_rn_nofuse(a[j], a[j]);
    for (int blk = 1; blk < 16; ++blk) {
#pragma unroll
      for (int j = 0; j < 8; ++j) {
        float p = mul_rn_nofuse(a[blk * 8 + j], a[blk * 8 + j]);
        r[j] = r[j] + p;
      }
    }
    float res = ((r[0] + r[1]) + (r[2] + r[3])) + ((r[4] + r[5]) + (r[6] + r[7]));
    if (half == 0) h0 = res; else h1 = res;
  }
  return h0 + h1;
}

// np-einsum SSE-order dot over 256 floats (gold-validated rounds 3-10).
__device__ __forceinline__ float np_dot256(const float* __restrict__ zr,
                                           const float* __restrict__ cr) {
  float A0 = 0.f, A1 = 0.f, A2 = 0.f, A3 = 0.f;
#pragma unroll 1
  for (int c16 = 0; c16 < 16; ++c16) {
    const float* zz = zr + c16 * 16;
    const float* cc = cr + c16 * 16;
#pragma unroll
    for (int s = 3; s >= 0; --s) {
      A0 = mul_rn_nofuse(zz[s * 4 + 0], cc[s * 4 + 0]) + A0;
      A1 = mul_rn_nofuse(zz[s * 4 + 1], cc[s * 4 + 1]) + A1;
      A2 = mul_rn_nofuse(zz[s * 4 + 2], cc[s * 4 + 2]) + A2;
      A3 = mul_rn_nofuse(zz[s * 4 + 3], cc[s * 4 + 3]) + A3;
    }
  }
  return (A0 + A1) + (A2 + A3);
}

// ---- prep: np-exact z_sq + fp16 transpose zT_h[b][n][d] (into d_out) ----
__global__ __launch_bounds__(64) void zprep_kernel(const float* __restrict__ z,
                                                   float* __restrict__ zsq,
                                                   f16* __restrict__ zT_h) {
  __shared__ float zs[64][LDP];
  int t = threadIdx.x;
  int b = blockIdx.x >> 6;
  int n0 = (blockIdx.x & 63) * 64;
  const float* zb = z + (size_t)b * DD * NP;
  for (int d = 0; d < DD; ++d) zs[t][d] = zb[(size_t)d * NP + n0 + t];
  __syncthreads();
  zsq[b * NP + n0 + t] = np_pairwise256_sq(&zs[t][0]);
  f16* ob = zT_h + ((size_t)b * NP + n0) * DD;
  for (int it = 0; it < 64; ++it) {
    union { f16 h[4]; uint2 u; } pk;
#pragma unroll
    for (int j = 0; j < 4; ++j) pk.h[j] = (f16)zs[it][t * 4 + j];
    *(uint2*)&ob[(size_t)it * DD + t * 4] = pk.u;
  }
}

// ---- prep: np-exact cb_sq + fp16 codebook copy (into d_out) ----
__global__ __launch_bounds__(64) void cbprep_kernel(const float* __restrict__ emb,
                                                    float* __restrict__ cbsq,
                                                    f16* __restrict__ cb_h) {
  __shared__ float cs[64][LDP];
  int t = threadIdx.x;
  int r0 = blockIdx.x * 64;
  const float4* e4 = (const float4*)emb;
  for (int rr = 0; rr < 64; ++rr) {
    float4 v = e4[(size_t)(r0 + rr) * 64 + t];
    *(float4*)&cs[rr][t * 4] = v;
  }
  __syncthreads();
  cbsq[r0 + t] = np_pairwise256_sq(&cs[t][0]);
  for (int rr = 0; rr < 64; ++rr) {
    union { f16 h[4]; uint2 u; } pk;
#pragma unroll
    for (int j = 0; j < 4; ++j) pk.h[j] = (f16)cs[rr][t * 4 + j];
    *(uint2*)&cb_h[(size_t)(r0 + rr) * DD + t * 4] = pk.u;
  }
}

// ---- phase 1: fp16 MFMA distances + top-2; z tile RESIDENT in LDS ----
// 4 waves (wm x wn = 2x2); block tile 128 n; per kt 64 k (wave: 64n x 32k).
__global__ __launch_bounds__(256) void vq_mfma_kernel(
    const f16* __restrict__ zT_h, const int* __restrict__ c,
    const f16* __restrict__ cb_h, const float* __restrict__ zsq,
    const float* __restrict__ cbsq, int* __restrict__ idx_out,
    unsigned int* __restrict__ counters, unsigned int* __restrict__ lists) {
  __shared__ __align__(16) f16 zs[128][264];  // 67.6 KB, resident all kt
  __shared__ __align__(16) f16 cs[64][72];    // 9.2 KB, cycled per (kt,dc)
  const int t = threadIdx.x;
  const int b = blockIdx.y;
  const int n0 = blockIdx.x * 128;
  const int wave = t >> 6;
  const int wm = wave >> 1, wn = wave & 1;
  const int l = t & 63, lr = l & 15, lg = l >> 4;
  const int cls = c[b];
  const f16* __restrict__ zTb = zT_h + ((size_t)b * NP + n0) * DD;
  const f16* __restrict__ cbb = cb_h + (size_t)cls * KC * DD;
  const float* __restrict__ cbsqb = cbsq + cls * KC;

  // stage z tile [128][256] f16 once (contiguous 64KB global block, b128 in/out)
#pragma unroll
  for (int i = 0; i < 16; ++i) {
    int flat = i * 256 + t;
    int row = flat >> 5, col8 = flat & 31;
    *(f16x8*)&zs[row][col8 * 8] = *(const f16x8*)&zTb[(size_t)row * DD + col8 * 8];
  }

  float zsqv[16];
#pragma unroll
  for (int mi = 0; mi < 4; ++mi)
#pragma unroll
    for (int rg = 0; rg < 4; ++rg)
      zsqv[mi * 4 + rg] = zsq[b * NP + n0 + wm * 64 + mi * 16 + lg * 4 + rg];

  float m1[16], m2[16];
  int i1[16];
#pragma unroll
  for (int r = 0; r < 16; ++r) { m1[r] = 3.4e38f; m2[r] = 3.4e38f; i1[r] = 0; }

#pragma unroll 1
  for (int kt = 0; kt < 8; ++kt) {
    const int k0 = kt * 64;
    f32x4 acc[4][2];
#pragma unroll
    for (int mi = 0; mi < 4; ++mi)
#pragma unroll
      for (int nj = 0; nj < 2; ++nj) acc[mi][nj] = (f32x4){0.f, 0.f, 0.f, 0.f};

#pragma unroll 1
    for (int dc = 0; dc < 4; ++dc) {
      const int d0g = dc * 64;
      __syncthreads();
      // stage cb chunk [64 k][64 d] f16
#pragma unroll
      for (int j = 0; j < 2; ++j) {
        int flat = j * 256 + t;
        int row = flat >> 3, col8 = flat & 7;
        *(f16x8*)&cs[row][col8 * 8] =
            *(const f16x8*)&cbb[(size_t)(k0 + row) * DD + d0g + col8 * 8];
      }
      __syncthreads();
#pragma unroll
      for (int s = 0; s < 2; ++s) {
        const int dz = d0g + s * 32 + lg * 8;  // into resident zs
        const int dcs = s * 32 + lg * 8;       // into cs chunk
        f16x8 af[4], bf[2];
#pragma unroll
        for (int mi = 0; mi < 4; ++mi)
          af[mi] = *(const f16x8*)&zs[wm * 64 + mi * 16 + lr][dz];
#pragma unroll
        for (int nj = 0; nj < 2; ++nj)
          bf[nj] = *(const f16x8*)&cs[wn * 32 + nj * 16 + lr][dcs];
#pragma unroll
        for (int mi = 0; mi < 4; ++mi)
#pragma unroll
          for (int nj = 0; nj < 2; ++nj)
            acc[mi][nj] = __builtin_amdgcn_mfma_f32_16x16x32_f16(
                af[mi], bf[nj], acc[mi][nj], 0, 0, 0);
      }
    }

    // epilogue: dist + per-row top-2 (k ascending per thread)
#pragma unroll
    for (int nj = 0; nj < 2; ++nj) {
      const int k = k0 + wn * 32 + nj * 16 + lr;
      const float cq = cbsqb[k];
#pragma unroll
      for (int mi = 0; mi < 4; ++mi)
#pragma unroll
        for (int rg = 0; rg < 4; ++rg) {
          const int ri = mi * 4 + rg;
          float dist = (zsqv[ri] - 2.0f * acc[mi][nj][rg]) + cq;
          if (dist < m1[ri]) {
            m2[ri] = m1[ri]; m1[ri] = dist; i1[ri] = k;
          } else if (dist < m2[ri]) {
            m2[ri] = dist;
          }
        }
    }
  }

  // top-2 butterfly across the 16 lanes (lr) sharing each row set
#pragma unroll
  for (int r = 0; r < 16; ++r) {
#pragma unroll
    for (int off = 8; off >= 1; off >>= 1) {
      float om1 = __shfl_xor(m1[r], off);
      float om2 = __shfl_xor(m2[r], off);
      int oi = __shfl_xor(i1[r], off);
      bool take = (om1 < m1[r]) || (om1 == m1[r] && oi < i1[r]);
      if (take) {
        m2[r] = fminf(m1[r], om2);
        m1[r] = om1;
        i1[r] = oi;
      } else {
        m2[r] = fminf(m2[r], om1);
      }
    }
  }

  // cross-wave (wn halves) merge via LDS overlay on zs (z no longer needed)
  __syncthreads();
  float* redm = (float*)&zs[0][0];   // [2][128][2]
  int* redi = (int*)(redm + 512);    // [2][128]
  if (lr == 0) {
#pragma unroll
    for (int r = 0; r < 16; ++r) {
      int row = wm * 64 + (r >> 2) * 16 + lg * 4 + (r & 3);
      redm[(wn * 128 + row) * 2 + 0] = m1[r];
      redm[(wn * 128 + row) * 2 + 1] = m2[r];
      redi[wn * 128 + row] = i1[r];
    }
  }
  __syncthreads();
  if (t < 128) {
    const int row = t;
    float a1 = redm[row * 2], a2 = redm[row * 2 + 1];
    int ai = redi[row];
    float b1 = redm[(128 + row) * 2], b2 = redm[(128 + row) * 2 + 1];
    int bi2 = redi[128 + row];
    float f1, f2;
    int idx;
    if (b1 < a1) { f1 = b1; idx = bi2; f2 = fminf(a1, b2); }
    else { f1 = a1; idx = ai; f2 = fminf(b1, a2); }
    const int n = n0 + row;
    idx_out[b * NP + n] = idx;
    if (f2 - f1 < EPS) {  // near-tie: queue into this class's fixlist
      unsigned p = atomicAdd(&counters[cls], 1u);
      if (p < PER_CLS) lists[cls * PER_CLS + p] = ((unsigned)b << 12) | (unsigned)n;
    }
  }
}

// ---- phase 2: np-exact re-resolution, LDS-staged (class-bucketed, P=8) ----
__global__ __launch_bounds__(256) void vq_fix_kernel(
    const float* __restrict__ z, const float* __restrict__ emb,
    const float* __restrict__ zsq, const float* __restrict__ cbsq,
    int* __restrict__ idx_out, const unsigned int* __restrict__ counters,
    const unsigned int* __restrict__ lists) {
  const int cls = blockIdx.x;
  unsigned cnt = counters[cls];
  if (cnt > PER_CLS) cnt = PER_CLS;
  const unsigned base = blockIdx.y * 8;
  if (base >= cnt) return;
  const int t = threadIdx.x;

  __shared__ float zrow[8][LDP];   // 8.3 KB (np source rows, fp32)
  __shared__ float cbt[32][LDP];   // 33.3 KB (codebook tile, fp32)
  __shared__ float zq[8];
  __shared__ unsigned bn[8];
  __shared__ float red_v[256];
  __shared__ int red_k[256];

  if (t < 8) {
    unsigned p = base + t;
    unsigned e = (p < cnt) ? lists[cls * PER_CLS + p] : 0xFFFFFFFFu;
    bn[t] = e;
    if (e != 0xFFFFFFFFu) zq[t] = zsq[(e >> 12) * NP + (e & (NP - 1))];
  }
  __syncthreads();
#pragma unroll
  for (int p = 0; p < 8; ++p) {
    unsigned e = bn[p];
    if (e != 0xFFFFFFFFu) {
      int bb = (int)(e >> 12), nn = (int)(e & (NP - 1));
      zrow[p][t] = z[((size_t)bb * DD + t) * NP + nn];
    }
  }

  const int myp = t & 7;
  const int mykrow = t >> 3;
  const bool valid = (bn[myp] != 0xFFFFFFFFu);
  float best = 3.4e38f;
  int bk = 0x7FFFFFFF;

#pragma unroll 1
  for (int tile = 0; tile < 16; ++tile) {
    __syncthreads();
    // stage cb tile [32 k][256 d] fp32, coalesced
#pragma unroll
    for (int j = 0; j < 8; ++j) {
      int flat = j * 256 + t;
      int row = flat >> 6, col4 = flat & 63;
      *(float4*)&cbt[row][col4 * 4] =
          *(const float4*)&emb[((size_t)cls * KC + tile * 32 + row) * DD + col4 * 4];
    }
    __syncthreads();
    if (valid) {
      const int k = tile * 32 + mykrow;   // ascending per thread over tiles
      float dot = np_dot256(&zrow[myp][0], &cbt[mykrow][0]);
      float dist = (zq[myp] - 2.0f * dot) + cbsq[cls * KC + k];
      if (dist < best) { best = dist; bk = k; }
    }
  }

  // reduce over the 32 threads sharing each p (stride-8 groups)
  red_v[t] = best;
  red_k[t] = bk;
  __syncthreads();
  for (int off = 128; off >= 8; off >>= 1) {
    if (t < off) {
      float ov = red_v[t + off];
      int ok = red_k[t + off];
      if (ov < red_v[t] || (ov == red_v[t] && ok < red_k[t])) {
        red_v[t] = ov;
        red_k[t] = ok;
      }
    }
    __syncthreads();
  }
  if (t < 8 && bn[t] != 0xFFFFFFFFu) {
    unsigned e = bn[t];
    idx_out[(e >> 12) * NP + (e & (NP - 1))] = red_k[t];
  }
}

// ---- gather selected rows -> [B,H,W,D] (bitwise copy; overwrites d_out) ----
__global__ __launch_bounds__(256) void vq_gather_kernel(
    const int* __restrict__ c, const float* __restrict__ emb,
    const int* __restrict__ idx, float* __restrict__ out) {
  int t = threadIdx.x;
  int r = blockIdx.x * 4 + (t >> 6);
  int lane = t & 63;
  int b = r >> 12;
  int k = idx[r];
  const float4* src = (const float4*)(emb + (size_t)(c[b] * KC + k) * DD);
  float4* dst = (float4*)(out + (size_t)r * DD);
  dst[lane] = src[lane];
}

extern "C" void kernel_launch(void* const* d_in, const int* in_sizes, int n_in,
                              void* d_out, int out_size, void* d_ws, size_t ws_size,
                              hipStream_t stream) {
  const float* z = (const float*)d_in[0];    // [32,256,64,64]
  const int* c = (const int*)d_in[1];        // [32]
  const float* emb = (const float*)d_in[2];  // [30720,256]
  float* out = (float*)d_out;                // [32,64,64,256] = 134.2 MB

  char* ws = (char*)d_ws;
  float* zsq = (float*)ws;                                   // 512 KB
  float* cbsq = (float*)(ws + 524288);                       // 120 KB
  int* idx = (int*)(ws + 655360);                            // 512 KB
  unsigned int* counters = (unsigned int*)(ws + 1179648);    // 256 B
  unsigned int* lists = (unsigned int*)(ws + 1179904);       // 480 KB

  f16* zT_h = (f16*)d_out;
  f16* cb_h = (f16*)((char*)d_out + (size_t)BB * NP * DD * 2);

  hipMemsetAsync(counters, 0, NCLS * sizeof(unsigned int), stream);
  zprep_kernel<<<BB * (NP / 64), 64, 0, stream>>>(z, zsq, zT_h);
  cbprep_kernel<<<(NCLS * KC) / 64, 64, 0, stream>>>(emb, cbsq, cb_h);
  dim3 gA(NP / 128, BB);
  vq_mfma_kernel<<<gA, 256, 0, stream>>>(zT_h, c, cb_h, zsq, cbsq, idx, counters, lists);
  dim3 gF(NCLS, PER_CLS / 8);
  vq_fix_kernel<<<gF, 256, 0, stream>>>(z, emb, zsq, cbsq, idx, counters, lists);
  vq_gather_kernel<<<(BB * NP) / 4, 256, 0, stream>>>(c, emb, idx, out);
}

// Round 12
// 429.259 us; speedup vs baseline: 1.8179x; 1.3441x over previous
//
#include <hip/hip_runtime.h>
#include <cstdint>

#define NCLS 60
#define KC 512
#define DD 256
#define BB 32
#define NP 4096
#define LDP 260
#define EPS 1e-2f      // provable fp16-vs-np dist bound ~6e-3; typical ~2e-4
#define PER_CLS 2048

typedef _Float16 f16;
typedef _Float16 f16x8 __attribute__((ext_vector_type(8)));
typedef float f32x4 __attribute__((ext_vector_type(4)));

__device__ __forceinline__ float mul_rn_nofuse(float a, float b) {
  float p = a * b;
  asm("" : "+v"(p));
  return p;
}

// numpy pairwise_sum of x*x over 256 contiguous floats.
__device__ __forceinline__ float np_pairwise256_sq(const float* row) {
  float h0 = 0.f, h1 = 0.f;
#pragma unroll
  for (int half = 0; half < 2; ++half) {
    const float* a = row + half * 128;
    float r[8];
#pragma unroll
    for (int j = 0; j < 8; ++j) r[j] = mul_rn_nofuse(a[j], a[j]);
    for (int blk = 1; blk < 16; ++blk) {
#pragma unroll
      for (int j = 0; j < 8; ++j) {
        float p = mul_rn_nofuse(a[blk * 8 + j], a[blk * 8 + j]);
        r[j] = r[j] + p;
      }
    }
    float res = ((r[0] + r[1]) + (r[2] + r[3])) + ((r[4] + r[5]) + (r[6] + r[7]));
    if (half == 0) h0 = res; else h1 = res;
  }
  return h0 + h1;
}

// np-einsum SSE-order dot over 256 floats (gold-validated rounds 3-11).
__device__ __forceinline__ float np_dot256(const float* __restrict__ zr,
                                           const float* __restrict__ cr) {
  float A0 = 0.f, A1 = 0.f, A2 = 0.f, A3 = 0.f;
#pragma unroll 1
  for (int c16 = 0; c16 < 16; ++c16) {
    const float* zz = zr + c16 * 16;
    const float* cc = cr + c16 * 16;
#pragma unroll
    for (int s = 3; s >= 0; --s) {
      A0 = mul_rn_nofuse(zz[s * 4 + 0], cc[s * 4 + 0]) + A0;
      A1 = mul_rn_nofuse(zz[s * 4 + 1], cc[s * 4 + 1]) + A1;
      A2 = mul_rn_nofuse(zz[s * 4 + 2], cc[s * 4 + 2]) + A2;
      A3 = mul_rn_nofuse(zz[s * 4 + 3], cc[s * 4 + 3]) + A3;
    }
  }
  return (A0 + A1) + (A2 + A3);
}

// ---- prep: np-exact z_sq + fp16 transpose zT_h[b][n][d] (into d_out) ----
__global__ __launch_bounds__(64) void zprep_kernel(const float* __restrict__ z,
                                                   float* __restrict__ zsq,
                                                   f16* __restrict__ zT_h) {
  __shared__ float zs[64][LDP];
  int t = threadIdx.x;
  int b = blockIdx.x >> 6;
  int n0 = (blockIdx.x & 63) * 64;
  const float* zb = z + (size_t)b * DD * NP;
  for (int d = 0; d < DD; ++d) zs[t][d] = zb[(size_t)d * NP + n0 + t];
  __syncthreads();
  zsq[b * NP + n0 + t] = np_pairwise256_sq(&zs[t][0]);
  f16* ob = zT_h + ((size_t)b * NP + n0) * DD;
  for (int it = 0; it < 64; ++it) {
    union { f16 h[4]; uint2 u; } pk;
#pragma unroll
    for (int j = 0; j < 4; ++j) pk.h[j] = (f16)zs[it][t * 4 + j];
    *(uint2*)&ob[(size_t)it * DD + t * 4] = pk.u;
  }
}

// ---- prep: np-exact cb_sq + fp16 codebook copy (into d_out) ----
__global__ __launch_bounds__(64) void cbprep_kernel(const float* __restrict__ emb,
                                                    float* __restrict__ cbsq,
                                                    f16* __restrict__ cb_h) {
  __shared__ float cs[64][LDP];
  int t = threadIdx.x;
  int r0 = blockIdx.x * 64;
  const float4* e4 = (const float4*)emb;
  for (int rr = 0; rr < 64; ++rr) {
    float4 v = e4[(size_t)(r0 + rr) * 64 + t];
    *(float4*)&cs[rr][t * 4] = v;
  }
  __syncthreads();
  cbsq[r0 + t] = np_pairwise256_sq(&cs[t][0]);
  for (int rr = 0; rr < 64; ++rr) {
    union { f16 h[4]; uint2 u; } pk;
#pragma unroll
    for (int j = 0; j < 4; ++j) pk.h[j] = (f16)cs[rr][t * 4 + j];
    *(uint2*)&cb_h[(size_t)(r0 + rr) * DD + t * 4] = pk.u;
  }
}

// ---- phase 1: fp16 MFMA + top-2, 2-phase reg-staged pipeline (T14) ----
// Block 256 thr = 4 waves (wm x wn = 2x2); block tile 64 n x 128 k per kt.
// 32 phases = 4 kt x 8 d-chunks(32). Per phase/wave: 6 ds_read_b128 + 8 MFMA;
// next chunk's 3 global loads issued BEFORE compute, written after, 1 barrier.
__global__ __launch_bounds__(256) void vq_mfma_kernel(
    const f16* __restrict__ zT_h, const int* __restrict__ c,
    const f16* __restrict__ cb_h, const float* __restrict__ zsq,
    const float* __restrict__ cbsq, int* __restrict__ idx_out,
    unsigned int* __restrict__ counters, unsigned int* __restrict__ lists) {
  __shared__ __align__(16) f16 zc[2][64][40];    // 10.0 KB
  __shared__ __align__(16) f16 cc[2][128][40];   // 20.0 KB
  const int t = threadIdx.x;
  const int b = blockIdx.y;
  const int n0 = blockIdx.x * 64;
  const int wave = t >> 6;
  const int wm = wave >> 1, wn = wave & 1;
  const int l = t & 63, lr = l & 15, lg = l >> 4;
  const int cls = c[b];
  const f16* __restrict__ zTb = zT_h + ((size_t)b * NP + n0) * DD;
  const f16* __restrict__ cbb = cb_h + (size_t)cls * KC * DD;
  const float* __restrict__ cbsqb = cbsq + cls * KC;
  const int srow = t >> 2, sseg = (t & 3) * 8;   // staging map: 16B units

  float zsqv[8];
#pragma unroll
  for (int mi = 0; mi < 2; ++mi)
#pragma unroll
    for (int rg = 0; rg < 4; ++rg)
      zsqv[mi * 4 + rg] = zsq[b * NP + n0 + wm * 32 + mi * 16 + lg * 4 + rg];

  float m1[8], m2[8];
  int i1[8];
#pragma unroll
  for (int r = 0; r < 8; ++r) { m1[r] = 3.4e38f; m2[r] = 3.4e38f; i1[r] = 0; }

  // prologue: stage chunk 0 (kt=0, dc=0)
  f16x8 rz, rc0, rc1;
  rz  = *(const f16x8*)&zTb[(size_t)srow * DD + sseg];
  rc0 = *(const f16x8*)&cbb[(size_t)srow * DD + sseg];
  rc1 = *(const f16x8*)&cbb[(size_t)(64 + srow) * DD + sseg];
  *(f16x8*)&zc[0][srow][sseg] = rz;
  *(f16x8*)&cc[0][srow][sseg] = rc0;
  *(f16x8*)&cc[0][64 + srow][sseg] = rc1;
  __syncthreads();

  f32x4 acc[2][4];
#pragma unroll
  for (int mi = 0; mi < 2; ++mi)
#pragma unroll
    for (int nj = 0; nj < 4; ++nj) acc[mi][nj] = (f32x4){0.f, 0.f, 0.f, 0.f};

#pragma unroll 1
  for (int p = 0; p < 32; ++p) {
    const int buf = p & 1;
    if (p < 31) {  // issue next chunk's loads (in flight during compute)
      const int kn = (p + 1) >> 3, dn = (p + 1) & 7;
      const int doff = dn * 32 + sseg;
      rz  = *(const f16x8*)&zTb[(size_t)srow * DD + doff];
      rc0 = *(const f16x8*)&cbb[((size_t)kn * 128 + srow) * DD + doff];
      rc1 = *(const f16x8*)&cbb[((size_t)kn * 128 + 64 + srow) * DD + doff];
    }
    // compute current chunk: one K32 step
    f16x8 af[2], bf[4];
#pragma unroll
    for (int mi = 0; mi < 2; ++mi)
      af[mi] = *(const f16x8*)&zc[buf][wm * 32 + mi * 16 + lr][lg * 8];
#pragma unroll
    for (int nj = 0; nj < 4; ++nj)
      bf[nj] = *(const f16x8*)&cc[buf][wn * 64 + nj * 16 + lr][lg * 8];
#pragma unroll
    for (int mi = 0; mi < 2; ++mi)
#pragma unroll
      for (int nj = 0; nj < 4; ++nj)
        acc[mi][nj] = __builtin_amdgcn_mfma_f32_16x16x32_f16(
            af[mi], bf[nj], acc[mi][nj], 0, 0, 0);

    if ((p & 7) == 7) {  // kt complete: dist + top-2, reset acc
      const int kt = p >> 3;
#pragma unroll
      for (int nj = 0; nj < 4; ++nj) {
        const int k = kt * 128 + wn * 64 + nj * 16 + lr;
        const float cq = cbsqb[k];
#pragma unroll
        for (int mi = 0; mi < 2; ++mi)
#pragma unroll
          for (int rg = 0; rg < 4; ++rg) {
            const int ri = mi * 4 + rg;
            float dist = (zsqv[ri] - 2.0f * acc[mi][nj][rg]) + cq;
            if (dist < m1[ri]) {
              m2[ri] = m1[ri]; m1[ri] = dist; i1[ri] = k;
            } else if (dist < m2[ri]) {
              m2[ri] = dist;
            }
          }
      }
#pragma unroll
      for (int mi = 0; mi < 2; ++mi)
#pragma unroll
        for (int nj = 0; nj < 4; ++nj) acc[mi][nj] = (f32x4){0.f, 0.f, 0.f, 0.f};
    }

    if (p < 31) {  // write next chunk into the other buffer (waits vmcnt)
      const int nb = buf ^ 1;
      *(f16x8*)&zc[nb][srow][sseg] = rz;
      *(f16x8*)&cc[nb][srow][sseg] = rc0;
      *(f16x8*)&cc[nb][64 + srow][sseg] = rc1;
    }
    __syncthreads();
  }

  // top-2 butterfly across the 16 lanes (lr) sharing each row set
#pragma unroll
  for (int r = 0; r < 8; ++r) {
#pragma unroll
    for (int off = 8; off >= 1; off >>= 1) {
      float om1 = __shfl_xor(m1[r], off);
      float om2 = __shfl_xor(m2[r], off);
      int oi = __shfl_xor(i1[r], off);
      bool take = (om1 < m1[r]) || (om1 == m1[r] && oi < i1[r]);
      if (take) {
        m2[r] = fminf(m1[r], om2);
        m1[r] = om1;
        i1[r] = oi;
      } else {
        m2[r] = fminf(m2[r], om1);
      }
    }
  }

  // cross-wave (wn halves) merge via LDS overlay (buffers dead after last phase)
  float* redm = (float*)&zc[0][0][0];  // [2][64][2]
  int* redi = (int*)&cc[0][0][0];      // [2][64]
  if (lr == 0) {
#pragma unroll
    for (int r = 0; r < 8; ++r) {
      int row = wm * 32 + (r >> 2) * 16 + lg * 4 + (r & 3);
      redm[(wn * 64 + row) * 2 + 0] = m1[r];
      redm[(wn * 64 + row) * 2 + 1] = m2[r];
      redi[wn * 64 + row] = i1[r];
    }
  }
  __syncthreads();
  if (t < 64) {
    const int row = t;
    float a1 = redm[row * 2], a2 = redm[row * 2 + 1];
    int ai = redi[row];
    float b1 = redm[(64 + row) * 2], b2 = redm[(64 + row) * 2 + 1];
    int bi2 = redi[64 + row];
    float f1, f2;
    int idx;
    if (b1 < a1) { f1 = b1; idx = bi2; f2 = fminf(a1, b2); }
    else { f1 = a1; idx = ai; f2 = fminf(b1, a2); }
    const int n = n0 + row;
    idx_out[b * NP + n] = idx;
    if (f2 - f1 < EPS) {
      unsigned p = atomicAdd(&counters[cls], 1u);
      if (p < PER_CLS) lists[cls * PER_CLS + p] = ((unsigned)b << 12) | (unsigned)n;
    }
  }
}

// ---- phase 2: np-exact re-resolution, LDS-staged (class-bucketed, P=8) ----
__global__ __launch_bounds__(256) void vq_fix_kernel(
    const float* __restrict__ z, const float* __restrict__ emb,
    const float* __restrict__ zsq, const float* __restrict__ cbsq,
    int* __restrict__ idx_out, const unsigned int* __restrict__ counters,
    const unsigned int* __restrict__ lists) {
  const int cls = blockIdx.x;
  unsigned cnt = counters[cls];
  if (cnt > PER_CLS) cnt = PER_CLS;
  const unsigned base = blockIdx.y * 8;
  if (base >= cnt) return;
  const int t = threadIdx.x;

  __shared__ float zrow[8][LDP];
  __shared__ float cbt[32][LDP];
  __shared__ float zq[8];
  __shared__ unsigned bn[8];
  __shared__ float red_v[256];
  __shared__ int red_k[256];

  if (t < 8) {
    unsigned p = base + t;
    unsigned e = (p < cnt) ? lists[cls * PER_CLS + p] : 0xFFFFFFFFu;
    bn[t] = e;
    if (e != 0xFFFFFFFFu) zq[t] = zsq[(e >> 12) * NP + (e & (NP - 1))];
  }
  __syncthreads();
#pragma unroll
  for (int p = 0; p < 8; ++p) {
    unsigned e = bn[p];
    if (e != 0xFFFFFFFFu) {
      int bb = (int)(e >> 12), nn = (int)(e & (NP - 1));
      zrow[p][t] = z[((size_t)bb * DD + t) * NP + nn];
    }
  }

  const int myp = t & 7;
  const int mykrow = t >> 3;
  const bool valid = (bn[myp] != 0xFFFFFFFFu);
  float best = 3.4e38f;
  int bk = 0x7FFFFFFF;

#pragma unroll 1
  for (int tile = 0; tile < 16; ++tile) {
    __syncthreads();
#pragma unroll
    for (int j = 0; j < 8; ++j) {
      int flat = j * 256 + t;
      int row = flat >> 6, col4 = flat & 63;
      *(float4*)&cbt[row][col4 * 4] =
          *(const float4*)&emb[((size_t)cls * KC + tile * 32 + row) * DD + col4 * 4];
    }
    __syncthreads();
    if (valid) {
      const int k = tile * 32 + mykrow;
      float dot = np_dot256(&zrow[myp][0], &cbt[mykrow][0]);
      float dist = (zq[myp] - 2.0f * dot) + cbsq[cls * KC + k];
      if (dist < best) { best = dist; bk = k; }
    }
  }

  red_v[t] = best;
  red_k[t] = bk;
  __syncthreads();
  for (int off = 128; off >= 8; off >>= 1) {
    if (t < off) {
      float ov = red_v[t + off];
      int ok = red_k[t + off];
      if (ov < red_v[t] || (ov == red_v[t] && ok < red_k[t])) {
        red_v[t] = ov;
        red_k[t] = ok;
      }
    }
    __syncthreads();
  }
  if (t < 8 && bn[t] != 0xFFFFFFFFu) {
    unsigned e = bn[t];
    idx_out[(e >> 12) * NP + (e & (NP - 1))] = red_k[t];
  }
}

// ---- gather selected rows -> [B,H,W,D] (bitwise copy; overwrites d_out) ----
__global__ __launch_bounds__(256) void vq_gather_kernel(
    const int* __restrict__ c, const float* __restrict__ emb,
    const int* __restrict__ idx, float* __restrict__ out) {
  int t = threadIdx.x;
  int r = blockIdx.x * 4 + (t >> 6);
  int lane = t & 63;
  int b = r >> 12;
  int k = idx[r];
  const float4* src = (const float4*)(emb + (size_t)(c[b] * KC + k) * DD);
  float4* dst = (float4*)(out + (size_t)r * DD);
  dst[lane] = src[lane];
}

extern "C" void kernel_launch(void* const* d_in, const int* in_sizes, int n_in,
                              void* d_out, int out_size, void* d_ws, size_t ws_size,
                              hipStream_t stream) {
  const float* z = (const float*)d_in[0];    // [32,256,64,64]
  const int* c = (const int*)d_in[1];        // [32]
  const float* emb = (const float*)d_in[2];  // [30720,256]
  float* out = (float*)d_out;                // [32,64,64,256] = 134.2 MB

  char* ws = (char*)d_ws;
  float* zsq = (float*)ws;                                   // 512 KB
  float* cbsq = (float*)(ws + 524288);                       // 120 KB
  int* idx = (int*)(ws + 655360);                            // 512 KB
  unsigned int* counters = (unsigned int*)(ws + 1179648);    // 256 B
  unsigned int* lists = (unsigned int*)(ws + 1179904);       // 480 KB

  f16* zT_h = (f16*)d_out;
  f16* cb_h = (f16*)((char*)d_out + (size_t)BB * NP * DD * 2);

  hipMemsetAsync(counters, 0, NCLS * sizeof(unsigned int), stream);
  zprep_kernel<<<BB * (NP / 64), 64, 0, stream>>>(z, zsq, zT_h);
  cbprep_kernel<<<(NCLS * KC) / 64, 64, 0, stream>>>(emb, cbsq, cb_h);
  dim3 gA(NP / 64, BB);
  vq_mfma_kernel<<<gA, 256, 0, stream>>>(zT_h, c, cb_h, zsq, cbsq, idx, counters, lists);
  dim3 gF(NCLS, PER_CLS / 8);
  vq_fix_kernel<<<gF, 256, 0, stream>>>(z, emb, zsq, cbsq, idx, counters, lists);
  vq_gather_kernel<<<(BB * NP) / 4, 256, 0, stream>>>(c, emb, idx, out);
}

// Round 13
// 408.529 us; speedup vs baseline: 1.9101x; 1.0507x over previous
//
#include <hip/hip_runtime.h>
#include <cstdint>

#define NCLS 60
#define KC 512
#define DD 256
#define BB 32
#define NP 4096
#define LDP 260
#define EPS 1e-2f      // provable fp16-vs-np dist bound ~6.5e-3
#define PER_CLS 2048

typedef _Float16 f16;
typedef _Float16 f16x8 __attribute__((ext_vector_type(8)));
typedef float f32x4 __attribute__((ext_vector_type(4)));

__device__ __forceinline__ float mul_rn_nofuse(float a, float b) {
  float p = a * b;
  asm("" : "+v"(p));
  return p;
}

// numpy pairwise_sum of x*x over 256 contiguous floats.
__device__ __forceinline__ float np_pairwise256_sq(const float* row) {
  float h0 = 0.f, h1 = 0.f;
#pragma unroll
  for (int half = 0; half < 2; ++half) {
    const float* a = row + half * 128;
    float r[8];
#pragma unroll
    for (int j = 0; j < 8; ++j) r[j] = mul_rn_nofuse(a[j], a[j]);
    for (int blk = 1; blk < 16; ++blk) {
#pragma unroll
      for (int j = 0; j < 8; ++j) {
        float p = mul_rn_nofuse(a[blk * 8 + j], a[blk * 8 + j]);
        r[j] = r[j] + p;
      }
    }
    float res = ((r[0] + r[1]) + (r[2] + r[3])) + ((r[4] + r[5]) + (r[6] + r[7]));
    if (half == 0) h0 = res; else h1 = res;
  }
  return h0 + h1;
}

// ---- prep: np-exact z_sq + fp16 transpose zT_h[b][n][d] (into d_out) ----
__global__ __launch_bounds__(64) void zprep_kernel(const float* __restrict__ z,
                                                   float* __restrict__ zsq,
                                                   f16* __restrict__ zT_h) {
  __shared__ float zs[64][LDP];
  int t = threadIdx.x;
  int b = blockIdx.x >> 6;
  int n0 = (blockIdx.x & 63) * 64;
  const float* zb = z + (size_t)b * DD * NP;
  for (int d = 0; d < DD; ++d) zs[t][d] = zb[(size_t)d * NP + n0 + t];
  __syncthreads();
  zsq[b * NP + n0 + t] = np_pairwise256_sq(&zs[t][0]);
  f16* ob = zT_h + ((size_t)b * NP + n0) * DD;
  for (int it = 0; it < 64; ++it) {
    union { f16 h[4]; uint2 u; } pk;
#pragma unroll
    for (int j = 0; j < 4; ++j) pk.h[j] = (f16)zs[it][t * 4 + j];
    *(uint2*)&ob[(size_t)it * DD + t * 4] = pk.u;
  }
}

// ---- prep: np-exact cb_sq + fp16 codebook copy (into d_out) ----
__global__ __launch_bounds__(64) void cbprep_kernel(const float* __restrict__ emb,
                                                    float* __restrict__ cbsq,
                                                    f16* __restrict__ cb_h) {
  __shared__ float cs[64][LDP];
  int t = threadIdx.x;
  int r0 = blockIdx.x * 64;
  const float4* e4 = (const float4*)emb;
  for (int rr = 0; rr < 64; ++rr) {
    float4 v = e4[(size_t)(r0 + rr) * 64 + t];
    *(float4*)&cs[rr][t * 4] = v;
  }
  __syncthreads();
  cbsq[r0 + t] = np_pairwise256_sq(&cs[t][0]);
  for (int rr = 0; rr < 64; ++rr) {
    union { f16 h[4]; uint2 u; } pk;
#pragma unroll
    for (int j = 0; j < 4; ++j) pk.h[j] = (f16)cs[rr][t * 4 + j];
    *(uint2*)&cb_h[(size_t)(r0 + rr) * DD + t * 4] = pk.u;
  }
}

// ---- phase 1: fp16 MFMA + top-2, 2-phase reg-staged pipeline (unchanged) ----
__global__ __launch_bounds__(256) void vq_mfma_kernel(
    const f16* __restrict__ zT_h, const int* __restrict__ c,
    const f16* __restrict__ cb_h, const float* __restrict__ zsq,
    const float* __restrict__ cbsq, int* __restrict__ idx_out,
    unsigned int* __restrict__ counters, unsigned int* __restrict__ lists) {
  __shared__ __align__(16) f16 zc[2][64][40];
  __shared__ __align__(16) f16 cc[2][128][40];
  const int t = threadIdx.x;
  const int b = blockIdx.y;
  const int n0 = blockIdx.x * 64;
  const int wave = t >> 6;
  const int wm = wave >> 1, wn = wave & 1;
  const int l = t & 63, lr = l & 15, lg = l >> 4;
  const int cls = c[b];
  const f16* __restrict__ zTb = zT_h + ((size_t)b * NP + n0) * DD;
  const f16* __restrict__ cbb = cb_h + (size_t)cls * KC * DD;
  const float* __restrict__ cbsqb = cbsq + cls * KC;
  const int srow = t >> 2, sseg = (t & 3) * 8;

  float zsqv[8];
#pragma unroll
  for (int mi = 0; mi < 2; ++mi)
#pragma unroll
    for (int rg = 0; rg < 4; ++rg)
      zsqv[mi * 4 + rg] = zsq[b * NP + n0 + wm * 32 + mi * 16 + lg * 4 + rg];

  float m1[8], m2[8];
  int i1[8];
#pragma unroll
  for (int r = 0; r < 8; ++r) { m1[r] = 3.4e38f; m2[r] = 3.4e38f; i1[r] = 0; }

  f16x8 rz, rc0, rc1;
  rz  = *(const f16x8*)&zTb[(size_t)srow * DD + sseg];
  rc0 = *(const f16x8*)&cbb[(size_t)srow * DD + sseg];
  rc1 = *(const f16x8*)&cbb[(size_t)(64 + srow) * DD + sseg];
  *(f16x8*)&zc[0][srow][sseg] = rz;
  *(f16x8*)&cc[0][srow][sseg] = rc0;
  *(f16x8*)&cc[0][64 + srow][sseg] = rc1;
  __syncthreads();

  f32x4 acc[2][4];
#pragma unroll
  for (int mi = 0; mi < 2; ++mi)
#pragma unroll
    for (int nj = 0; nj < 4; ++nj) acc[mi][nj] = (f32x4){0.f, 0.f, 0.f, 0.f};

#pragma unroll 1
  for (int p = 0; p < 32; ++p) {
    const int buf = p & 1;
    if (p < 31) {
      const int kn = (p + 1) >> 3, dn = (p + 1) & 7;
      const int doff = dn * 32 + sseg;
      rz  = *(const f16x8*)&zTb[(size_t)srow * DD + doff];
      rc0 = *(const f16x8*)&cbb[((size_t)kn * 128 + srow) * DD + doff];
      rc1 = *(const f16x8*)&cbb[((size_t)kn * 128 + 64 + srow) * DD + doff];
    }
    f16x8 af[2], bf[4];
#pragma unroll
    for (int mi = 0; mi < 2; ++mi)
      af[mi] = *(const f16x8*)&zc[buf][wm * 32 + mi * 16 + lr][lg * 8];
#pragma unroll
    for (int nj = 0; nj < 4; ++nj)
      bf[nj] = *(const f16x8*)&cc[buf][wn * 64 + nj * 16 + lr][lg * 8];
#pragma unroll
    for (int mi = 0; mi < 2; ++mi)
#pragma unroll
      for (int nj = 0; nj < 4; ++nj)
        acc[mi][nj] = __builtin_amdgcn_mfma_f32_16x16x32_f16(
            af[mi], bf[nj], acc[mi][nj], 0, 0, 0);

    if ((p & 7) == 7) {
      const int kt = p >> 3;
#pragma unroll
      for (int nj = 0; nj < 4; ++nj) {
        const int k = kt * 128 + wn * 64 + nj * 16 + lr;
        const float cq = cbsqb[k];
#pragma unroll
        for (int mi = 0; mi < 2; ++mi)
#pragma unroll
          for (int rg = 0; rg < 4; ++rg) {
            const int ri = mi * 4 + rg;
            float dist = (zsqv[ri] - 2.0f * acc[mi][nj][rg]) + cq;
            if (dist < m1[ri]) {
              m2[ri] = m1[ri]; m1[ri] = dist; i1[ri] = k;
            } else if (dist < m2[ri]) {
              m2[ri] = dist;
            }
          }
      }
#pragma unroll
      for (int mi = 0; mi < 2; ++mi)
#pragma unroll
        for (int nj = 0; nj < 4; ++nj) acc[mi][nj] = (f32x4){0.f, 0.f, 0.f, 0.f};
    }

    if (p < 31) {
      const int nb = buf ^ 1;
      *(f16x8*)&zc[nb][srow][sseg] = rz;
      *(f16x8*)&cc[nb][srow][sseg] = rc0;
      *(f16x8*)&cc[nb][64 + srow][sseg] = rc1;
    }
    __syncthreads();
  }

#pragma unroll
  for (int r = 0; r < 8; ++r) {
#pragma unroll
    for (int off = 8; off >= 1; off >>= 1) {
      float om1 = __shfl_xor(m1[r], off);
      float om2 = __shfl_xor(m2[r], off);
      int oi = __shfl_xor(i1[r], off);
      bool take = (om1 < m1[r]) || (om1 == m1[r] && oi < i1[r]);
      if (take) {
        m2[r] = fminf(m1[r], om2);
        m1[r] = om1;
        i1[r] = oi;
      } else {
        m2[r] = fminf(m2[r], om1);
      }
    }
  }

  float* redm = (float*)&zc[0][0][0];
  int* redi = (int*)&cc[0][0][0];
  if (lr == 0) {
#pragma unroll
    for (int r = 0; r < 8; ++r) {
      int row = wm * 32 + (r >> 2) * 16 + lg * 4 + (r & 3);
      redm[(wn * 64 + row) * 2 + 0] = m1[r];
      redm[(wn * 64 + row) * 2 + 1] = m2[r];
      redi[wn * 64 + row] = i1[r];
    }
  }
  __syncthreads();
  if (t < 64) {
    const int row = t;
    float a1 = redm[row * 2], a2 = redm[row * 2 + 1];
    int ai = redi[row];
    float b1 = redm[(64 + row) * 2], b2 = redm[(64 + row) * 2 + 1];
    int bi2 = redi[64 + row];
    float f1, f2;
    int idx;
    if (b1 < a1) { f1 = b1; idx = bi2; f2 = fminf(a1, b2); }
    else { f1 = a1; idx = ai; f2 = fminf(b1, a2); }
    const int n = n0 + row;
    idx_out[b * NP + n] = idx;
    if (f2 - f1 < EPS) {
      unsigned p = atomicAdd(&counters[cls], 1u);
      if (p < PER_CLS) lists[cls * PER_CLS + p] = ((unsigned)b << 12) | (unsigned)n;
    }
  }
}

// ---- phase 2: np-exact re-resolution; P=32 positions, 2x2 register tile ----
// Thread: pg=t&15 owns positions {pg, pg+16}; kg=t>>4 owns krows {kg, kg+16}
// per 32-k tile. Shared 16-float chunks amortize LDS: 1KB/dot (was 2KB).
__global__ __launch_bounds__(256) void vq_fix_kernel(
    const float* __restrict__ z, const float* __restrict__ emb,
    const float* __restrict__ zsq, const float* __restrict__ cbsq,
    int* __restrict__ idx_out, const unsigned int* __restrict__ counters,
    const unsigned int* __restrict__ lists) {
  const int cls = blockIdx.x;
  unsigned cnt = counters[cls];
  if (cnt > PER_CLS) cnt = PER_CLS;
  const unsigned base = blockIdx.y * 32;
  if (base >= cnt) return;
  const int t = threadIdx.x;

  __shared__ float zrow[32][LDP];   // 33.3 KB; read rows=pg: 2-way banks (free)
  __shared__ float cbt[32][LDP];    // 33.3 KB; read rows=kg quads: broadcast
  __shared__ float zq[32];
  __shared__ unsigned bn[32];
  __shared__ float red_v[256];
  __shared__ int red_k[256];

  if (t < 32) {
    unsigned p = base + t;
    unsigned e = (p < cnt) ? lists[cls * PER_CLS + p] : 0xFFFFFFFFu;
    bn[t] = e;
    zq[t] = (e != 0xFFFFFFFFu) ? zsq[(e >> 12) * NP + (e & (NP - 1))] : 0.f;
  }
  __syncthreads();
  // stage 32 z-rows (strided gather): 8 threads per row, 32 d's each
  {
    int r = t >> 3, d0 = t & 7;
    unsigned e = bn[r];
    if (e != 0xFFFFFFFFu) {
      int bb = (int)(e >> 12), nn = (int)(e & (NP - 1));
      const float* zp = z + (size_t)bb * DD * NP + nn;
#pragma unroll
      for (int j = 0; j < 32; ++j) zrow[r][d0 + j * 8] = zp[(size_t)(d0 + j * 8) * NP];
    }
  }

  const int pg = t & 15;
  const int kg = t >> 4;
  const bool val0 = (bn[pg] != 0xFFFFFFFFu);
  const bool val1 = (bn[pg + 16] != 0xFFFFFFFFu);
  float best[2] = {3.4e38f, 3.4e38f};
  int bk[2] = {0x7FFFFFFF, 0x7FFFFFFF};

#pragma unroll 1
  for (int tile = 0; tile < 16; ++tile) {
    __syncthreads();  // previous tile consumed + zrow staged (tile 0)
    // stage cb tile [32 k][256 d] fp32, coalesced (one row per 64-lane group)
#pragma unroll
    for (int j = 0; j < 8; ++j) {
      int flat = j * 256 + t;
      int row = flat >> 6, col4 = flat & 63;
      *(float4*)&cbt[row][col4 * 4] =
          *(const float4*)&emb[((size_t)cls * KC + tile * 32 + row) * DD + col4 * 4];
    }
    __syncthreads();

    // 2 positions x 2 krows, np-chain order per pair (c16 asc, s=3..0, 4 accs)
    float A[2][2][4];
#pragma unroll
    for (int ps = 0; ps < 2; ++ps)
#pragma unroll
      for (int ks = 0; ks < 2; ++ks)
#pragma unroll
        for (int ll = 0; ll < 4; ++ll) A[ps][ks][ll] = 0.f;

#pragma unroll 1
    for (int c16 = 0; c16 < 16; ++c16) {
      float za[2][16], ca[2][16];
#pragma unroll
      for (int q = 0; q < 4; ++q) {
        *(float4*)&za[0][q * 4] = *(const float4*)&zrow[pg][c16 * 16 + q * 4];
        *(float4*)&za[1][q * 4] = *(const float4*)&zrow[pg + 16][c16 * 16 + q * 4];
        *(float4*)&ca[0][q * 4] = *(const float4*)&cbt[kg][c16 * 16 + q * 4];
        *(float4*)&ca[1][q * 4] = *(const float4*)&cbt[kg + 16][c16 * 16 + q * 4];
      }
#pragma unroll
      for (int s = 3; s >= 0; --s)
#pragma unroll
        for (int ps = 0; ps < 2; ++ps)
#pragma unroll
          for (int ks = 0; ks < 2; ++ks)
#pragma unroll
            for (int ll = 0; ll < 4; ++ll) {
              float p = mul_rn_nofuse(za[ps][s * 4 + ll], ca[ks][s * 4 + ll]);
              A[ps][ks][ll] = p + A[ps][ks][ll];
            }
    }

    // fold: ks=0 (k=tile*32+kg) before ks=1 (+16): ascending per thread
#pragma unroll
    for (int ps = 0; ps < 2; ++ps) {
      const float zqv = zq[pg + 16 * ps];
#pragma unroll
      for (int ks = 0; ks < 2; ++ks) {
        const int k = tile * 32 + kg + 16 * ks;
        float dot = (A[ps][ks][0] + A[ps][ks][1]) + (A[ps][ks][2] + A[ps][ks][3]);
        float dist = (zqv - 2.0f * dot) + cbsq[cls * KC + k];
        if (dist < best[ps]) { best[ps] = dist; bk[ps] = k; }
      }
    }
  }

  // reduce over the 16 kg-threads sharing each position; two slots sequentially
#pragma unroll
  for (int s = 0; s < 2; ++s) {
    __syncthreads();
    red_v[t] = best[s];
    red_k[t] = bk[s];
    __syncthreads();
    for (int off = 8; off >= 1; off >>= 1) {
      if (kg < off) {
        int o = t + 16 * off;
        float ov = red_v[o];
        int ok = red_k[o];
        if (ov < red_v[t] || (ov == red_v[t] && ok < red_k[t])) {
          red_v[t] = ov;
          red_k[t] = ok;
        }
      }
      __syncthreads();
    }
    if (kg == 0) {
      unsigned e = bn[pg + 16 * s];
      if (e != 0xFFFFFFFFu && ((s == 0 && val0) || (s == 1 && val1)))
        idx_out[(e >> 12) * NP + (e & (NP - 1))] = red_k[t];
    }
  }
}

// ---- gather selected rows -> [B,H,W,D] (bitwise copy; overwrites d_out) ----
__global__ __launch_bounds__(256) void vq_gather_kernel(
    const int* __restrict__ c, const float* __restrict__ emb,
    const int* __restrict__ idx, float* __restrict__ out) {
  int t = threadIdx.x;
  int r = blockIdx.x * 4 + (t >> 6);
  int lane = t & 63;
  int b = r >> 12;
  int k = idx[r];
  const float4* src = (const float4*)(emb + (size_t)(c[b] * KC + k) * DD);
  float4* dst = (float4*)(out + (size_t)r * DD);
  dst[lane] = src[lane];
}

extern "C" void kernel_launch(void* const* d_in, const int* in_sizes, int n_in,
                              void* d_out, int out_size, void* d_ws, size_t ws_size,
                              hipStream_t stream) {
  const float* z = (const float*)d_in[0];    // [32,256,64,64]
  const int* c = (const int*)d_in[1];        // [32]
  const float* emb = (const float*)d_in[2];  // [30720,256]
  float* out = (float*)d_out;                // [32,64,64,256] = 134.2 MB

  char* ws = (char*)d_ws;
  float* zsq = (float*)ws;                                   // 512 KB
  float* cbsq = (float*)(ws + 524288);                       // 120 KB
  int* idx = (int*)(ws + 655360);                            // 512 KB
  unsigned int* counters = (unsigned int*)(ws + 1179648);    // 256 B
  unsigned int* lists = (unsigned int*)(ws + 1179904);       // 480 KB

  f16* zT_h = (f16*)d_out;
  f16* cb_h = (f16*)((char*)d_out + (size_t)BB * NP * DD * 2);

  hipMemsetAsync(counters, 0, NCLS * sizeof(unsigned int), stream);
  zprep_kernel<<<BB * (NP / 64), 64, 0, stream>>>(z, zsq, zT_h);
  cbprep_kernel<<<(NCLS * KC) / 64, 64, 0, stream>>>(emb, cbsq, cb_h);
  dim3 gA(NP / 64, BB);
  vq_mfma_kernel<<<gA, 256, 0, stream>>>(zT_h, c, cb_h, zsq, cbsq, idx, counters, lists);
  dim3 gF(NCLS, PER_CLS / 32);
  vq_fix_kernel<<<gF, 256, 0, stream>>>(z, emb, zsq, cbsq, idx, counters, lists);
  vq_gather_kernel<<<(BB * NP) / 4, 256, 0, stream>>>(c, emb, idx, out);
}

// Round 14
// 402.412 us; speedup vs baseline: 1.9391x; 1.0152x over previous
//
#include <hip/hip_runtime.h>
#include <cstdint>

#define NCLS 60
#define KC 512
#define DD 256
#define BB 32
#define NP 4096
#define LDP 260
#define EPS 1e-2f
#define PER_CLS 2048

typedef _Float16 f16;
typedef _Float16 f16x8 __attribute__((ext_vector_type(8)));
typedef float f32x4 __attribute__((ext_vector_type(4)));
typedef unsigned long long u64;

__device__ __forceinline__ float mul_rn_nofuse(float a, float b) {
  float p = a * b;
  asm("" : "+v"(p));
  return p;
}

// numpy pairwise_sum of x*x over 256 contiguous floats.
__device__ __forceinline__ float np_pairwise256_sq(const float* row) {
  float h0 = 0.f, h1 = 0.f;
#pragma unroll
  for (int half = 0; half < 2; ++half) {
    const float* a = row + half * 128;
    float r[8];
#pragma unroll
    for (int j = 0; j < 8; ++j) r[j] = mul_rn_nofuse(a[j], a[j]);
    for (int blk = 1; blk < 16; ++blk) {
#pragma unroll
      for (int j = 0; j < 8; ++j) {
        float p = mul_rn_nofuse(a[blk * 8 + j], a[blk * 8 + j]);
        r[j] = r[j] + p;
      }
    }
    float res = ((r[0] + r[1]) + (r[2] + r[3])) + ((r[4] + r[5]) + (r[6] + r[7]));
    if (half == 0) h0 = res; else h1 = res;
  }
  return h0 + h1;
}

// ---- prep: np-exact z_sq + fp16 transpose zT_h[b][n][d] (into d_out) ----
__global__ __launch_bounds__(64) void zprep_kernel(const float* __restrict__ z,
                                                   float* __restrict__ zsq,
                                                   f16* __restrict__ zT_h) {
  __shared__ float zs[64][LDP];
  int t = threadIdx.x;
  int b = blockIdx.x >> 6;
  int n0 = (blockIdx.x & 63) * 64;
  const float* zb = z + (size_t)b * DD * NP;
  for (int d = 0; d < DD; ++d) zs[t][d] = zb[(size_t)d * NP + n0 + t];
  __syncthreads();
  zsq[b * NP + n0 + t] = np_pairwise256_sq(&zs[t][0]);
  f16* ob = zT_h + ((size_t)b * NP + n0) * DD;
  for (int it = 0; it < 64; ++it) {
    union { f16 h[4]; uint2 u; } pk;
#pragma unroll
    for (int j = 0; j < 4; ++j) pk.h[j] = (f16)zs[it][t * 4 + j];
    *(uint2*)&ob[(size_t)it * DD + t * 4] = pk.u;
  }
}

// ---- prep: np-exact cb_sq + fp16 codebook copy (into d_out) ----
__global__ __launch_bounds__(64) void cbprep_kernel(const float* __restrict__ emb,
                                                    float* __restrict__ cbsq,
                                                    f16* __restrict__ cb_h) {
  __shared__ float cs[64][LDP];
  int t = threadIdx.x;
  int r0 = blockIdx.x * 64;
  const float4* e4 = (const float4*)emb;
  for (int rr = 0; rr < 64; ++rr) {
    float4 v = e4[(size_t)(r0 + rr) * 64 + t];
    *(float4*)&cs[rr][t * 4] = v;
  }
  __syncthreads();
  cbsq[r0 + t] = np_pairwise256_sq(&cs[t][0]);
  for (int rr = 0; rr < 64; ++rr) {
    union { f16 h[4]; uint2 u; } pk;
#pragma unroll
    for (int j = 0; j < 4; ++j) pk.h[j] = (f16)cs[rr][t * 4 + j];
    *(uint2*)&cb_h[(size_t)(r0 + rr) * DD + t * 4] = pk.u;
  }
}

// ---- phase 1: fp16 MFMA + top-2, depth-2 reg-staged pipeline, raw barriers --
// Loads for phase q issued at phase q-2 (2-phase latency cover); raw s_barrier
// (no vmcnt drain) + manual lgkmcnt(0) keeps prefetch loads in flight.
#define LOADSET(RZ, RC0, RC1, q)                                               \
  do {                                                                         \
    const int kn_ = (q) >> 3, dn_ = (q) & 7;                                   \
    const int doff_ = dn_ * 32 + sseg;                                         \
    RZ = *(const f16x8*)&zTb[(size_t)srow * DD + doff_];                       \
    RC0 = *(const f16x8*)&cbb[((size_t)kn_ * 128 + srow) * DD + doff_];        \
    RC1 = *(const f16x8*)&cbb[((size_t)kn_ * 128 + 64 + srow) * DD + doff_];   \
  } while (0)

#define WRITESET(B, RZ, RC0, RC1)                                              \
  do {                                                                         \
    *(f16x8*)&zc[B][srow][sseg] = RZ;                                          \
    *(f16x8*)&cc[B][srow][sseg] = RC0;                                         \
    *(f16x8*)&cc[B][64 + srow][sseg] = RC1;                                    \
  } while (0)

#define PIPE_BARRIER()                                                         \
  do {                                                                         \
    asm volatile("s_waitcnt lgkmcnt(0)" ::: "memory");                         \
    __builtin_amdgcn_sched_barrier(0);                                         \
    __builtin_amdgcn_s_barrier();                                              \
    __builtin_amdgcn_sched_barrier(0);                                         \
  } while (0)

#define COMPUTE(B, P)                                                          \
  do {                                                                         \
    f16x8 af[2], bf[4];                                                        \
    _Pragma("unroll") for (int mi = 0; mi < 2; ++mi)                           \
        af[mi] = *(const f16x8*)&zc[B][wm * 32 + mi * 16 + lr][lg * 8];        \
    _Pragma("unroll") for (int nj = 0; nj < 4; ++nj)                           \
        bf[nj] = *(const f16x8*)&cc[B][wn * 64 + nj * 16 + lr][lg * 8];        \
    _Pragma("unroll") for (int mi = 0; mi < 2; ++mi)                           \
        _Pragma("unroll") for (int nj = 0; nj < 4; ++nj)                       \
            acc[mi][nj] = __builtin_amdgcn_mfma_f32_16x16x32_f16(              \
                af[mi], bf[nj], acc[mi][nj], 0, 0, 0);                         \
    if (((P) & 7) == 7) {                                                      \
      const int kt_ = (P) >> 3;                                                \
      _Pragma("unroll") for (int nj = 0; nj < 4; ++nj) {                       \
        const int k_ = kt_ * 128 + wn * 64 + nj * 16 + lr;                     \
        const float cq_ = cbsqb[k_];                                           \
        _Pragma("unroll") for (int mi = 0; mi < 2; ++mi)                       \
            _Pragma("unroll") for (int rg = 0; rg < 4; ++rg) {                 \
          const int ri_ = mi * 4 + rg;                                         \
          float dist_ = (zsqv[ri_] - 2.0f * acc[mi][nj][rg]) + cq_;            \
          if (dist_ < m1[ri_]) {                                               \
            m2[ri_] = m1[ri_]; m1[ri_] = dist_; i1[ri_] = k_;                  \
          } else if (dist_ < m2[ri_]) {                                        \
            m2[ri_] = dist_;                                                   \
          }                                                                    \
        }                                                                      \
      }                                                                        \
      _Pragma("unroll") for (int mi = 0; mi < 2; ++mi)                         \
          _Pragma("unroll") for (int nj = 0; nj < 4; ++nj)                     \
              acc[mi][nj] = (f32x4){0.f, 0.f, 0.f, 0.f};                       \
    }                                                                          \
  } while (0)

__global__ __launch_bounds__(256) void vq_mfma_kernel(
    const f16* __restrict__ zT_h, const int* __restrict__ c,
    const f16* __restrict__ cb_h, const float* __restrict__ zsq,
    const float* __restrict__ cbsq, int* __restrict__ idx_out,
    unsigned int* __restrict__ counters, unsigned int* __restrict__ lists) {
  __shared__ __align__(16) f16 zc[2][64][40];
  __shared__ __align__(16) f16 cc[2][128][40];
  const int t = threadIdx.x;
  const int b = blockIdx.y;
  const int n0 = blockIdx.x * 64;
  const int wave = t >> 6;
  const int wm = wave >> 1, wn = wave & 1;
  const int l = t & 63, lr = l & 15, lg = l >> 4;
  const int cls = c[b];
  const f16* __restrict__ zTb = zT_h + ((size_t)b * NP + n0) * DD;
  const f16* __restrict__ cbb = cb_h + (size_t)cls * KC * DD;
  const float* __restrict__ cbsqb = cbsq + cls * KC;
  const int srow = t >> 2, sseg = (t & 3) * 8;

  float zsqv[8];
#pragma unroll
  for (int mi = 0; mi < 2; ++mi)
#pragma unroll
    for (int rg = 0; rg < 4; ++rg)
      zsqv[mi * 4 + rg] = zsq[b * NP + n0 + wm * 32 + mi * 16 + lg * 4 + rg];

  float m1[8], m2[8];
  int i1[8];
#pragma unroll
  for (int r = 0; r < 8; ++r) { m1[r] = 3.4e38f; m2[r] = 3.4e38f; i1[r] = 0; }

  f32x4 acc[2][4];
#pragma unroll
  for (int mi = 0; mi < 2; ++mi)
#pragma unroll
    for (int nj = 0; nj < 4; ++nj) acc[mi][nj] = (f32x4){0.f, 0.f, 0.f, 0.f};

  // prologue: buf0 <- phase0; issue phase1 into setB
  f16x8 rza, rc0a, rc1a, rzb, rc0b, rc1b;
  LOADSET(rza, rc0a, rc1a, 0);
  WRITESET(0, rza, rc0a, rc1a);  // compiler inserts counted vmcnt for these regs
  LOADSET(rzb, rc0b, rc1b, 1);
  PIPE_BARRIER();

#pragma unroll 1
  for (int pp = 0; pp < 16; ++pp) {
    const int p0 = pp * 2, p1 = p0 + 1;
    if (pp < 15) LOADSET(rza, rc0a, rc1a, p0 + 2);  // for phase p0+2
    COMPUTE(0, p0);
    WRITESET(1, rzb, rc0b, rc1b);  // phase p0+1 data (issued at p0-1: ~2 phases old)
    PIPE_BARRIER();
    if (pp < 15) LOADSET(rzb, rc0b, rc1b, p1 + 2);  // for phase p1+2
    COMPUTE(1, p1);
    if (pp < 15) {
      WRITESET(0, rza, rc0a, rc1a);  // phase p1+1 data
      PIPE_BARRIER();
    }
  }

  // top-2 butterfly across the 16 lanes (lr) sharing each row set
#pragma unroll
  for (int r = 0; r < 8; ++r) {
#pragma unroll
    for (int off = 8; off >= 1; off >>= 1) {
      float om1 = __shfl_xor(m1[r], off);
      float om2 = __shfl_xor(m2[r], off);
      int oi = __shfl_xor(i1[r], off);
      bool take = (om1 < m1[r]) || (om1 == m1[r] && oi < i1[r]);
      if (take) {
        m2[r] = fminf(m1[r], om2);
        m1[r] = om1;
        i1[r] = oi;
      } else {
        m2[r] = fminf(m2[r], om1);
      }
    }
  }

  // cross-wave merge via LDS overlay on zc[0]/cc[0] (phase-31 readers use [1])
  float* redm = (float*)&zc[0][0][0];
  int* redi = (int*)&cc[0][0][0];
  if (lr == 0) {
#pragma unroll
    for (int r = 0; r < 8; ++r) {
      int row = wm * 32 + (r >> 2) * 16 + lg * 4 + (r & 3);
      redm[(wn * 64 + row) * 2 + 0] = m1[r];
      redm[(wn * 64 + row) * 2 + 1] = m2[r];
      redi[wn * 64 + row] = i1[r];
    }
  }
  __syncthreads();
  if (t < 64) {
    const int row = t;
    float a1 = redm[row * 2], a2 = redm[row * 2 + 1];
    int ai = redi[row];
    float b1 = redm[(64 + row) * 2], b2 = redm[(64 + row) * 2 + 1];
    int bi2 = redi[64 + row];
    float f1, f2;
    int idx;
    if (b1 < a1) { f1 = b1; idx = bi2; f2 = fminf(a1, b2); }
    else { f1 = a1; idx = ai; f2 = fminf(b1, a2); }
    const int n = n0 + row;
    idx_out[b * NP + n] = idx;
    if (f2 - f1 < EPS) {
      unsigned p = atomicAdd(&counters[cls], 1u);
      if (p < PER_CLS) lists[cls * PER_CLS + p] = ((unsigned)b << 12) | (unsigned)n;
    }
  }
}

// ---- phase 2: np-exact re-resolution, k-split x8, packed atomicMin merge ----
__global__ __launch_bounds__(256) void vq_fix_kernel(
    const float* __restrict__ z, const float* __restrict__ emb,
    const float* __restrict__ zsq, const float* __restrict__ cbsq,
    u64* __restrict__ best_g, const unsigned int* __restrict__ counters,
    const unsigned int* __restrict__ lists) {
  const int cls = blockIdx.x;
  unsigned cnt = counters[cls];
  if (cnt > PER_CLS) cnt = PER_CLS;
  const int grp = blockIdx.y >> 3;
  const int kz = blockIdx.y & 7;
  const unsigned base = grp * 32;
  if (base >= cnt) return;
  const int t = threadIdx.x;

  __shared__ float zrow[32][LDP];
  __shared__ float cbt[32][LDP];
  __shared__ float zq[32];
  __shared__ unsigned bn[32];
  __shared__ float red_v[256];
  __shared__ int red_k[256];

  if (t < 32) {
    unsigned p = base + t;
    unsigned e = (p < cnt) ? lists[cls * PER_CLS + p] : 0xFFFFFFFFu;
    bn[t] = e;
    zq[t] = (e != 0xFFFFFFFFu) ? zsq[(e >> 12) * NP + (e & (NP - 1))] : 0.f;
  }
  __syncthreads();
  {
    int r = t >> 3, d0 = t & 7;
    unsigned e = bn[r];
    if (e != 0xFFFFFFFFu) {
      int bb = (int)(e >> 12), nn = (int)(e & (NP - 1));
      const float* zp = z + (size_t)bb * DD * NP + nn;
#pragma unroll
      for (int j = 0; j < 32; ++j) zrow[r][d0 + j * 8] = zp[(size_t)(d0 + j * 8) * NP];
    }
  }

  const int pg = t & 15;
  const int kg = t >> 4;
  const bool val0 = (bn[pg] != 0xFFFFFFFFu);
  const bool val1 = (bn[pg + 16] != 0xFFFFFFFFu);
  float best[2] = {3.4e38f, 3.4e38f};
  int bk[2] = {0x7FFFFFFF, 0x7FFFFFFF};

#pragma unroll 1
  for (int tt = 0; tt < 2; ++tt) {
    const int tile = kz * 2 + tt;
    __syncthreads();
#pragma unroll
    for (int j = 0; j < 8; ++j) {
      int flat = j * 256 + t;
      int row = flat >> 6, col4 = flat & 63;
      *(float4*)&cbt[row][col4 * 4] =
          *(const float4*)&emb[((size_t)cls * KC + tile * 32 + row) * DD + col4 * 4];
    }
    __syncthreads();

    float A[2][2][4];
#pragma unroll
    for (int ps = 0; ps < 2; ++ps)
#pragma unroll
      for (int ks = 0; ks < 2; ++ks)
#pragma unroll
        for (int ll = 0; ll < 4; ++ll) A[ps][ks][ll] = 0.f;

#pragma unroll 1
    for (int c16 = 0; c16 < 16; ++c16) {
      float za[2][16], ca[2][16];
#pragma unroll
      for (int q = 0; q < 4; ++q) {
        *(float4*)&za[0][q * 4] = *(const float4*)&zrow[pg][c16 * 16 + q * 4];
        *(float4*)&za[1][q * 4] = *(const float4*)&zrow[pg + 16][c16 * 16 + q * 4];
        *(float4*)&ca[0][q * 4] = *(const float4*)&cbt[kg][c16 * 16 + q * 4];
        *(float4*)&ca[1][q * 4] = *(const float4*)&cbt[kg + 16][c16 * 16 + q * 4];
      }
#pragma unroll
      for (int s = 3; s >= 0; --s)
#pragma unroll
        for (int ps = 0; ps < 2; ++ps)
#pragma unroll
          for (int ks = 0; ks < 2; ++ks)
#pragma unroll
            for (int ll = 0; ll < 4; ++ll) {
              float p = mul_rn_nofuse(za[ps][s * 4 + ll], ca[ks][s * 4 + ll]);
              A[ps][ks][ll] = p + A[ps][ks][ll];
            }
    }

#pragma unroll
    for (int ps = 0; ps < 2; ++ps) {
      const float zqv = zq[pg + 16 * ps];
#pragma unroll
      for (int ks = 0; ks < 2; ++ks) {
        const int k = tile * 32 + kg + 16 * ks;
        float dot = (A[ps][ks][0] + A[ps][ks][1]) + (A[ps][ks][2] + A[ps][ks][3]);
        float dist = (zqv - 2.0f * dot) + cbsq[cls * KC + k];
        if (dist < best[ps]) { best[ps] = dist; bk[ps] = k; }
      }
    }
  }

#pragma unroll
  for (int s = 0; s < 2; ++s) {
    __syncthreads();
    red_v[t] = best[s];
    red_k[t] = bk[s];
    __syncthreads();
    for (int off = 8; off >= 1; off >>= 1) {
      if (kg < off) {
        int o = t + 16 * off;
        float ov = red_v[o];
        int ok = red_k[o];
        if (ov < red_v[t] || (ov == red_v[t] && ok < red_k[t])) {
          red_v[t] = ov;
          red_k[t] = ok;
        }
      }
      __syncthreads();
    }
    if (kg == 0 && ((s == 0 && val0) || (s == 1 && val1))) {
      unsigned e = bn[pg + 16 * s];
      unsigned u = __float_as_uint(red_v[t]);
      u = (u & 0x80000000u) ? ~u : (u | 0x80000000u);  // order-preserving
      u64 pkd = ((u64)u << 32) | (unsigned)red_k[t];
      atomicMin(&best_g[(e >> 12) * NP + (e & (NP - 1))], pkd);
    }
  }
}

// ---- commit: unpack merged best into idx (flagged entries only) ----
__global__ __launch_bounds__(256) void vq_commit_kernel(
    const u64* __restrict__ best_g, const unsigned int* __restrict__ counters,
    const unsigned int* __restrict__ lists, int* __restrict__ idx_out) {
  const int cls = blockIdx.x;
  unsigned cnt = counters[cls];
  if (cnt > PER_CLS) cnt = PER_CLS;
  for (unsigned i = threadIdx.x; i < cnt; i += 256) {
    unsigned e = lists[cls * PER_CLS + i];
    int pos = (int)(e >> 12) * NP + (int)(e & (NP - 1));
    u64 v = best_g[pos];
    if (v != ~0ull) idx_out[pos] = (int)(unsigned)(v & 0xFFFFFFFFu);
  }
}

// ---- gather selected rows -> [B,H,W,D] (bitwise copy; overwrites d_out) ----
__global__ __launch_bounds__(256) void vq_gather_kernel(
    const int* __restrict__ c, const float* __restrict__ emb,
    const int* __restrict__ idx, float* __restrict__ out) {
  int t = threadIdx.x;
  int r = blockIdx.x * 4 + (t >> 6);
  int lane = t & 63;
  int b = r >> 12;
  int k = idx[r];
  const float4* src = (const float4*)(emb + (size_t)(c[b] * KC + k) * DD);
  float4* dst = (float4*)(out + (size_t)r * DD);
  dst[lane] = src[lane];
}

extern "C" void kernel_launch(void* const* d_in, const int* in_sizes, int n_in,
                              void* d_out, int out_size, void* d_ws, size_t ws_size,
                              hipStream_t stream) {
  const float* z = (const float*)d_in[0];    // [32,256,64,64]
  const int* c = (const int*)d_in[1];        // [32]
  const float* emb = (const float*)d_in[2];  // [30720,256]
  float* out = (float*)d_out;                // [32,64,64,256] = 134.2 MB

  char* ws = (char*)d_ws;
  float* zsq = (float*)ws;                                   // 512 KB
  float* cbsq = (float*)(ws + 524288);                       // 120 KB
  int* idx = (int*)(ws + 655360);                            // 512 KB
  unsigned int* counters = (unsigned int*)(ws + 1179648);    // 256 B
  unsigned int* lists = (unsigned int*)(ws + 1179904);       // 480 KB

  // d_out spare space: zT_h (67.1 MB) + cb_h (15.7 MB) + best (1 MB);
  // gather fully overwrites d_out last.
  f16* zT_h = (f16*)d_out;
  f16* cb_h = (f16*)((char*)d_out + (size_t)BB * NP * DD * 2);
  u64* best_g = (u64*)((char*)d_out + 82837504);

  hipMemsetAsync(counters, 0, NCLS * sizeof(unsigned int), stream);
  hipMemsetAsync(best_g, 0xFF, (size_t)BB * NP * 8, stream);
  zprep_kernel<<<BB * (NP / 64), 64, 0, stream>>>(z, zsq, zT_h);
  cbprep_kernel<<<(NCLS * KC) / 64, 64, 0, stream>>>(emb, cbsq, cb_h);
  dim3 gA(NP / 64, BB);
  vq_mfma_kernel<<<gA, 256, 0, stream>>>(zT_h, c, cb_h, zsq, cbsq, idx, counters, lists);
  dim3 gF(NCLS, (PER_CLS / 32) * 8);
  vq_fix_kernel<<<gF, 256, 0, stream>>>(z, emb, zsq, cbsq, best_g, counters, lists);
  vq_commit_kernel<<<NCLS, 256, 0, stream>>>(best_g, counters, lists, idx);
  vq_gather_kernel<<<(BB * NP) / 4, 256, 0, stream>>>(c, emb, idx, out);
}